// Round 1
// baseline (2356.564 us; speedup 1.0000x reference)
//
#include <hip/hip_runtime.h>

// Problem dims
#define Bn 128
#define Sn 512
#define In 128
#define Hn 128
#define Mn 8
#define Rn 16
#define KDn 16
#define On 128

// d_out float offsets: outputs[B,S,O], hiddens[S,B,M,H], attn_in[S,B,M,H],
// attn_comm[S,B,M,H], attn_rim[S,B,M,M]
static const size_t OUT_OUTPUTS = 0;
static const size_t OUT_HID   = (size_t)Bn * Sn * On;                 // 8388608
static const size_t OUT_AIN   = OUT_HID + (size_t)Sn * Bn * Mn * Hn;  // 75497472
static const size_t OUT_ACOMM = OUT_AIN + (size_t)Sn * Bn * Mn * Hn;  // 142606336
static const size_t OUT_ATTN  = OUT_ACOMM + (size_t)Sn * Bn * Mn * Hn;// 209715200

// ---------------------------------------------------------------------------
// K0: build combined B matrix Bcomb[128][2048]:
//   cols 0..1023   : Ba[j][m*128+h] = W_in[m,j,h]            (A_in GEMM)
//   cols 1024..2047: Bc[j][m*128+o] = sum_i W_in[m,j,i]*Wp[m,o,i]  (P GEMM)
// Stashed at the start of the outputs region (overwritten later by K3).
// ---------------------------------------------------------------------------
__global__ __launch_bounds__(128) void k0_prep(const float* __restrict__ Win,
                                               const float* __restrict__ Wp,
                                               float* __restrict__ Bcomb) {
  const int m = blockIdx.x >> 7;
  const int j = blockIdx.x & 127;
  const int t = threadIdx.x;
  __shared__ __align__(16) float row[128];
  __shared__ __align__(16) float wp[128][129];  // +1 pad: conflict-free row reads
#pragma unroll
  for (int it = 0; it < 32; ++it) {
    const int f4 = t + (it << 7);
    const int o = f4 >> 5;
    const int i4 = (f4 & 31) << 2;
    const float4 v = *(const float4*)&Wp[(size_t)((m << 7) + o) * 128 + i4];
    wp[o][i4] = v.x; wp[o][i4 + 1] = v.y; wp[o][i4 + 2] = v.z; wp[o][i4 + 3] = v.w;
  }
  row[t] = Win[(size_t)(((m << 7) + j) << 7) + t];
  __syncthreads();
  Bcomb[(size_t)j * 2048 + (m << 7) + t] = row[t];
  float acc = 0.f;
#pragma unroll 8
  for (int i = 0; i < 128; ++i) acc = fmaf(row[i], wp[t][i], acc);
  Bcomb[(size_t)j * 2048 + 1024 + (m << 7) + t] = acc;
}

// ---------------------------------------------------------------------------
// K1: fp32 GEMM [65536 x 128] x [128 x 2048] -> A_in (attn_in region) and
// P (attn_comm region). 128x128 tile, 256 threads, 8x8 microtile, K-chunk 32.
// x row r = b*S+s; output row orow = s*B+b.
// ---------------------------------------------------------------------------
__global__ __launch_bounds__(256) void k1_gemm_in(const float* __restrict__ X,
                                                  const float* __restrict__ Bcomb,
                                                  float* __restrict__ outAin,
                                                  float* __restrict__ outP) {
  const int ct = blockIdx.x;   // 0..15 col tiles
  const int rt = blockIdx.y;   // 0..511 row tiles
  const int tid = threadIdx.x;
  const int tx = tid & 15;
  const int ty = tid >> 4;
  __shared__ __align__(16) float As[32][132];
  __shared__ __align__(16) float Bs[32][132];
  const int rbase = rt << 7;
  const int cbase = ct << 7;
  float acc[8][8];
#pragma unroll
  for (int i = 0; i < 8; ++i) {
#pragma unroll
    for (int j = 0; j < 8; ++j) acc[i][j] = 0.f;
  }

  for (int kc = 0; kc < 4; ++kc) {
    const int k0 = kc << 5;
    __syncthreads();
#pragma unroll
    for (int it = 0; it < 4; ++it) {
      const int f4 = tid + (it << 8);
      const int row = f4 >> 3;
      const int kg = (f4 & 7) << 2;
      const float4 v = *(const float4*)&X[(size_t)(rbase + row) * 128 + k0 + kg];
      As[kg][row] = v.x; As[kg + 1][row] = v.y; As[kg + 2][row] = v.z; As[kg + 3][row] = v.w;
    }
#pragma unroll
    for (int it = 0; it < 4; ++it) {
      const int f4 = tid + (it << 8);
      const int kk = f4 >> 5;
      const int c4 = (f4 & 31) << 2;
      *(float4*)&Bs[kk][c4] = *(const float4*)&Bcomb[(size_t)(k0 + kk) * 2048 + cbase + c4];
    }
    __syncthreads();
#pragma unroll
    for (int kk = 0; kk < 32; ++kk) {
      const float4 a0 = *(const float4*)&As[kk][ty << 3];
      const float4 a1 = *(const float4*)&As[kk][(ty << 3) + 4];
      const float4 b0 = *(const float4*)&Bs[kk][tx << 3];
      const float4 b1 = *(const float4*)&Bs[kk][(tx << 3) + 4];
      const float av[8] = {a0.x, a0.y, a0.z, a0.w, a1.x, a1.y, a1.z, a1.w};
      const float bv[8] = {b0.x, b0.y, b0.z, b0.w, b1.x, b1.y, b1.z, b1.w};
#pragma unroll
      for (int i = 0; i < 8; ++i) {
#pragma unroll
        for (int j = 0; j < 8; ++j) acc[i][j] = fmaf(av[i], bv[j], acc[i][j]);
      }
    }
  }
  const bool isA = (ct < 8);
  float* dst = isA ? outAin : outP;
  const int cl = (isA ? cbase : (cbase - 1024)) + (tx << 3);
#pragma unroll
  for (int i = 0; i < 8; ++i) {
    const int r = rbase + (ty << 3) + i;
    const int bb = r >> 9;           // x row r = b*512+s
    const int ss = r & 511;
    const size_t orow = ((size_t)ss << 7) + bb;  // out row = s*128+b
    float4 v0 = make_float4(acc[i][0], acc[i][1], acc[i][2], acc[i][3]);
    float4 v1 = make_float4(acc[i][4], acc[i][5], acc[i][6], acc[i][7]);
    *(float4*)&dst[orow * 1024 + cl] = v0;
    *(float4*)&dst[orow * 1024 + cl + 4] = v1;
  }
}

// ---------------------------------------------------------------------------
// K2: the sequential recurrence. 1 block / batch, 8 waves = 8 mechanisms,
// lane holds h = {2*lane, 2*lane+1}. Weights in registers, reduce-scatter
// butterflies for the R/KD dots, double-buffered LDS, 1 barrier/step.
// Reads P from attn_comm region and overwrites it with A_comm.
// ---------------------------------------------------------------------------
__device__ __forceinline__ float fast_tanh(float x) {
  const float e = __expf(x + x);
  return fmaf(-2.f, __builtin_amdgcn_rcpf(e + 1.f), 1.f);
}

template <int HALF>
__device__ __forceinline__ void scat_level(const float* in, float* out, int lane, int lvl) {
  const bool hi = (lane >> lvl) & 1;
#pragma unroll
  for (int i = 0; i < HALF; ++i) {
    const float snd = hi ? in[i] : in[HALF + i];
    const float got = __shfl_xor(snd, 1 << lvl);
    out[i] = (hi ? in[HALF + i] : in[i]) + got;
  }
}

__global__ __launch_bounds__(512, 2) void k2_recur(
    const float* __restrict__ Uw, const float* __restrict__ Vw,
    const float* __restrict__ WQ, const float* __restrict__ WK,
    const float* __restrict__ WV, const float* __restrict__ bp,
    const float* __restrict__ cb, float* Pio,
    float* __restrict__ Hid, float* __restrict__ Attn) {
  const int b = blockIdx.x;
  const int tid = threadIdx.x;
  const int w = tid >> 6;     // mechanism
  const int lane = tid & 63;
  const int h0 = lane << 1;
  const int h1 = h0 + 1;

  __shared__ __align__(16) float VcL[2][8][128];
  __shared__ __align__(16) float QKL[2][8][36];  // Q: cols 0..15, K: 16..31; pad->36 (bank spread)
  __shared__ __align__(16) float TL[8][16];

  float u0[16], u1[16], v0r[16], v1r[16], wq0[16], wq1[16], wk0[16], wk1[16];
#pragma unroll
  for (int r = 0; r < 16; ++r) {
    u0[r]  = Uw[(size_t)(((w << 7) + h0) << 4) + r];
    u1[r]  = Uw[(size_t)(((w << 7) + h1) << 4) + r];
    v0r[r] = Vw[(size_t)(((w << 4) + r) << 7) + h0];
    v1r[r] = Vw[(size_t)(((w << 4) + r) << 7) + h1];
    wq0[r] = WQ[(size_t)(((w << 7) + h0) << 4) + r];
    wq1[r] = WQ[(size_t)(((w << 7) + h1) << 4) + r];
    wk0[r] = WK[(size_t)(((w << 7) + h0) << 4) + r];
    wk1[r] = WK[(size_t)(((w << 7) + h1) << 4) + r];
  }
  const float wv0 = WV[(size_t)((w << 7) + h0) * 128 + h0];  // diag(W_V)
  const float wv1 = WV[(size_t)((w << 7) + h1) * 128 + h1];
  const float bias0 = bp[(w << 7) + h0] + cb[(w << 7) + h0];
  const float bias1 = bp[(w << 7) + h1] + cb[(w << 7) + h1];

  // bit-reversal: value index landing in this lane after reduce-scatter
  const int brev4 = ((lane & 1) << 3) | ((lane & 2) << 1) | ((lane & 4) >> 1) | ((lane & 8) >> 3);
  const int brev5 = ((lane & 1) << 4) | ((lane & 2) << 2) | (lane & 4) | ((lane & 8) >> 2) | ((lane & 16) >> 4);
  const int mm = lane >> 3;
  const int nn = lane & 7;

  const size_t rowoff = (size_t)b * 1024 + (w << 7) + h0;
  const float2* pP = (const float2*)Pio + (rowoff >> 1);
  float2* pA = (float2*)Pio + (rowoff >> 1);
  float2* pH = (float2*)Hid + (rowoff >> 1);
  float* pAt = Attn + ((size_t)b << 6) + lane;

  float hs0 = 0.f, hs1 = 0.f;   // H state
  float2 pc = pP[0];            // P[0]
  int buf = 0;

  for (int s = 0; s < Sn; ++s) {
    // ---------- phase A: rec, tanh, Vc, Q/K partials ----------
    float tp[16];
#pragma unroll
    for (int r = 0; r < 16; ++r) tp[r] = fmaf(hs0, u0[r], hs1 * u1[r]);
    float t8[8], t4[4], t2[2], t1[1];
    scat_level<8>(tp, t8, lane, 0);
    scat_level<4>(t8, t4, lane, 1);
    scat_level<2>(t4, t2, lane, 2);
    scat_level<1>(t2, t1, lane, 3);
    float tv = t1[0];
    tv += __shfl_xor(tv, 16);
    tv += __shfl_xor(tv, 32);
    if (lane < 16) TL[w][brev4] = tv;  // wave-internal LDS, in-order DS pipe
    float tg[16];
#pragma unroll
    for (int ii = 0; ii < 4; ++ii) {
      const float4 q = *(const float4*)&TL[w][ii << 2];
      tg[(ii << 2) + 0] = q.x; tg[(ii << 2) + 1] = q.y;
      tg[(ii << 2) + 2] = q.z; tg[(ii << 2) + 3] = q.w;
    }
    float rec0 = 0.f, rec1 = 0.f;
#pragma unroll
    for (int r = 0; r < 16; ++r) {
      rec0 = fmaf(tg[r], v0r[r], rec0);
      rec1 = fmaf(tg[r], v1r[r], rec1);
    }
    const float hin0 = fast_tanh(pc.x + rec0 + bias0);
    const float hin1 = fast_tanh(pc.y + rec1 + bias1);
    *(float2*)&VcL[buf][w][h0] = make_float2(hin0 * wv0, hin1 * wv1);
    float qk[32];
#pragma unroll
    for (int k = 0; k < 16; ++k) {
      qk[k]      = fmaf(hin0, wq0[k], hin1 * wq1[k]);
      qk[16 + k] = fmaf(hin0, wk0[k], hin1 * wk1[k]);
    }
    float q16[16], q8[8], q4[4], q2[2], q1[1];
    scat_level<16>(qk, q16, lane, 0);
    scat_level<8>(q16, q8, lane, 1);
    scat_level<4>(q8, q4, lane, 2);
    scat_level<2>(q4, q2, lane, 3);
    scat_level<1>(q2, q1, lane, 4);
    float qv = q1[0];
    qv += __shfl_xor(qv, 32);
    if (lane < 32) QKL[buf][w][brev5] = qv;
    __syncthreads();
    // prefetch next P right after the barrier (no barrier before its use)
    float2 pn = make_float2(0.f, 0.f);
    if (s + 1 < Sn) pn = pP[(size_t)(s + 1) * 65536];
    // ---------- phase B: attention + outputs ----------
    float sc = 0.f;
#pragma unroll
    for (int ii = 0; ii < 4; ++ii) {
      const float4 q = *(const float4*)&QKL[buf][mm][ii << 2];
      const float4 kv = *(const float4*)&QKL[buf][nn][16 + (ii << 2)];
      sc = fmaf(q.x, kv.x, sc); sc = fmaf(q.y, kv.y, sc);
      sc = fmaf(q.z, kv.z, sc); sc = fmaf(q.w, kv.w, sc);
    }
    sc *= 0.25f;  // 1/sqrt(KD=16)
    float mx = sc;
    mx = fmaxf(mx, __shfl_xor(mx, 1));
    mx = fmaxf(mx, __shfl_xor(mx, 2));
    mx = fmaxf(mx, __shfl_xor(mx, 4));
    const float ex = __expf(sc - mx);
    float sm = ex;
    sm += __shfl_xor(sm, 1);
    sm += __shfl_xor(sm, 2);
    sm += __shfl_xor(sm, 4);
    const float at = ex * __builtin_amdgcn_rcpf(sm);  // attn[mm][nn]
    if (w == 0) pAt[(size_t)s * 8192] = at;
    float ac0 = 0.f, ac1 = 0.f;
#pragma unroll
    for (int mo = 0; mo < 8; ++mo) {
      const float a = __shfl(at, (mo << 3) + w);  // attn[mo][n=w]
      const float2 vc = *(const float2*)&VcL[buf][mo][h0];
      ac0 = fmaf(a, vc.x, ac0);
      ac1 = fmaf(a, vc.y, ac1);
    }
    const float hn0 = hin0 + ac0;
    const float hn1 = hin1 + ac1;
    pH[(size_t)s * 65536] = make_float2(hn0, hn1);
    pA[(size_t)s * 65536] = make_float2(ac0, ac1);  // overwrites P[s] (already consumed)
    hs0 = hn0; hs1 = hn1;
    pc = pn;
    buf ^= 1;
  }
}

// ---------------------------------------------------------------------------
// K3: out = hiddens[65536 x 1024] @ Wo^T [1024 x 128] + bo -> outputs [B,S,O].
// Same GEMM skeleton; Wo transposed on the fly through LDS.
// ---------------------------------------------------------------------------
__global__ __launch_bounds__(256) void k3_out(const float* __restrict__ Hid,
                                              const float* __restrict__ Wo,
                                              const float* __restrict__ bo,
                                              float* __restrict__ Out) {
  const int rt = blockIdx.x;  // 0..511
  const int tid = threadIdx.x;
  const int tx = tid & 15;
  const int ty = tid >> 4;
  __shared__ __align__(16) float As[32][132];
  __shared__ __align__(16) float Bs[32][132];
  const int rbase = rt << 7;
  float acc[8][8];
#pragma unroll
  for (int i = 0; i < 8; ++i) {
#pragma unroll
    for (int j = 0; j < 8; ++j) acc[i][j] = 0.f;
  }

  for (int kc = 0; kc < 32; ++kc) {
    const int k0 = kc << 5;
    __syncthreads();
#pragma unroll
    for (int it = 0; it < 4; ++it) {
      const int f4 = tid + (it << 8);
      const int row = f4 >> 3;
      const int kg = (f4 & 7) << 2;
      const float4 v = *(const float4*)&Hid[(size_t)(rbase + row) * 1024 + k0 + kg];
      As[kg][row] = v.x; As[kg + 1][row] = v.y; As[kg + 2][row] = v.z; As[kg + 3][row] = v.w;
    }
#pragma unroll
    for (int it = 0; it < 4; ++it) {
      const int f4 = tid + (it << 8);
      const int o = f4 >> 3;
      const int kg = (f4 & 7) << 2;
      const float4 v = *(const float4*)&Wo[(size_t)o * 1024 + k0 + kg];
      Bs[kg][o] = v.x; Bs[kg + 1][o] = v.y; Bs[kg + 2][o] = v.z; Bs[kg + 3][o] = v.w;
    }
    __syncthreads();
#pragma unroll
    for (int kk = 0; kk < 32; ++kk) {
      const float4 a0 = *(const float4*)&As[kk][ty << 3];
      const float4 a1 = *(const float4*)&As[kk][(ty << 3) + 4];
      const float4 b0 = *(const float4*)&Bs[kk][tx << 3];
      const float4 b1 = *(const float4*)&Bs[kk][(tx << 3) + 4];
      const float av[8] = {a0.x, a0.y, a0.z, a0.w, a1.x, a1.y, a1.z, a1.w};
      const float bv[8] = {b0.x, b0.y, b0.z, b0.w, b1.x, b1.y, b1.z, b1.w};
#pragma unroll
      for (int i = 0; i < 8; ++i) {
#pragma unroll
        for (int j = 0; j < 8; ++j) acc[i][j] = fmaf(av[i], bv[j], acc[i][j]);
      }
    }
  }
  float bv[8];
#pragma unroll
  for (int j = 0; j < 8; ++j) bv[j] = bo[(tx << 3) + j];
#pragma unroll
  for (int i = 0; i < 8; ++i) {
    const int r = rbase + (ty << 3) + i;   // hiddens row = s*128+b
    const int ss = r >> 7;
    const int bb = r & 127;
    const size_t orow = ((size_t)bb << 9) + ss;  // outputs row = b*512+s
    float4 v0 = make_float4(acc[i][0] + bv[0], acc[i][1] + bv[1],
                            acc[i][2] + bv[2], acc[i][3] + bv[3]);
    float4 v1 = make_float4(acc[i][4] + bv[4], acc[i][5] + bv[5],
                            acc[i][6] + bv[6], acc[i][7] + bv[7]);
    *(float4*)&Out[orow * 128 + (tx << 3)] = v0;
    *(float4*)&Out[orow * 128 + (tx << 3) + 4] = v1;
  }
}

// ---------------------------------------------------------------------------
extern "C" void kernel_launch(void* const* d_in, const int* in_sizes, int n_in,
                              void* d_out, int out_size, void* d_ws, size_t ws_size,
                              hipStream_t stream) {
  const float* x    = (const float*)d_in[0];
  const float* Wp   = (const float*)d_in[1];
  const float* bp   = (const float*)d_in[2];
  const float* U    = (const float*)d_in[3];
  const float* V    = (const float*)d_in[4];
  const float* cbi  = (const float*)d_in[5];
  const float* Win  = (const float*)d_in[6];
  const float* WQ   = (const float*)d_in[7];
  const float* WK   = (const float*)d_in[8];
  const float* WV   = (const float*)d_in[9];
  const float* Wo   = (const float*)d_in[10];
  const float* bo   = (const float*)d_in[11];
  float* out = (float*)d_out;

  float* Bcomb = out + OUT_OUTPUTS;  // weight stash; overwritten by K3 at the end
  float* Hid   = out + OUT_HID;
  float* Ain   = out + OUT_AIN;
  float* Pbuf  = out + OUT_ACOMM;    // P staged here, overwritten by A_comm in K2
  float* Attn  = out + OUT_ATTN;

  hipLaunchKernelGGL(k0_prep, dim3(1024), dim3(128), 0, stream, Win, Wp, Bcomb);
  hipLaunchKernelGGL(k1_gemm_in, dim3(16, 512), dim3(256), 0, stream, x, Bcomb, Ain, Pbuf);
  hipLaunchKernelGGL(k2_recur, dim3(128), dim3(512), 0, stream,
                     U, V, WQ, WK, WV, bp, cbi, Pbuf, Hid, Attn);
  hipLaunchKernelGGL(k3_out, dim3(512), dim3(256), 0, stream, Hid, Wo, bo, out);
}